// Round 1
// baseline (945.833 us; speedup 1.0000x reference)
//
#include <hip/hip_runtime.h>

// Problem constants
#define NB 8
#define NC 128
#define NH 64
#define NW 64
#define HEADS 4
#define HP 32
#define WP 32
#define NTOK 1024     // HP*WP
#define TOPK 32
#define HDIM 32

// ---------------------------------------------------------------
// avg pool 2x2 on x and y
__global__ void k_pool(const float* __restrict__ x, const float* __restrict__ y,
                       float* __restrict__ xp, float* __restrict__ yp) {
  int idx = blockIdx.x * 256 + threadIdx.x;
  const int total = NB * NC * HP * WP; // 1,048,576
  if (idx >= 2 * total) return;
  bool isY = idx >= total;
  int i = isY ? idx - total : idx;
  int pw = i & 31, ph = (i >> 5) & 31, bc = i >> 10;
  const float* src = (isY ? y : x) + ((size_t)bc * 64 + ph * 2) * 64 + pw * 2;
  float v = 0.25f * (src[0] + src[1] + src[64] + src[65]);
  (isY ? yp : xp)[i] = v;
}

// ---------------------------------------------------------------
// 1x1 conv: out[b][co][p] = bias[co] + sum_ci w[co][ci] * in[b][ci][p]
// thread computes 8 consecutive co at one p
template <int CO>
__global__ void k_conv1x1(const float* __restrict__ in, const float* __restrict__ wt,
                          const float* __restrict__ bias, float* __restrict__ out) {
  int t = blockIdx.x * 256 + threadIdx.x;
  const int CG = CO / 8;
  int p = t & 1023;
  int rest = t >> 10;
  int cg = rest % CG;
  int b = rest / CG;
  if (b >= NB) return;
  const float* ip = in + (size_t)b * NC * NTOK + p;
  float acc[8];
#pragma unroll
  for (int i = 0; i < 8; i++) acc[i] = bias[cg * 8 + i];
  for (int ci = 0; ci < NC; ci++) {
    float mv = ip[ci * NTOK];
#pragma unroll
    for (int i = 0; i < 8; i++) acc[i] = fmaf(wt[(cg * 8 + i) * NC + ci], mv, acc[i]);
  }
#pragma unroll
  for (int i = 0; i < 8; i++) out[((size_t)b * CO + cg * 8 + i) * NTOK + p] = acc[i];
}

// ---------------------------------------------------------------
// depthwise 3x3 pad=1 on (B,128,32,32)
__global__ void k_dw3(const float* __restrict__ in, const float* __restrict__ wt,
                      const float* __restrict__ bias, float* __restrict__ out) {
  int t = blockIdx.x * 256 + threadIdx.x;
  if (t >= NB * NC * NTOK) return;
  int p = t & 1023;
  int pw = p & 31, ph = p >> 5;
  int bc = t >> 10;
  int c = bc & 127;
  const float* ip = in + (size_t)bc * NTOK;
  const float* wp = wt + c * 9;
  float acc = bias[c];
#pragma unroll
  for (int ky = 0; ky < 3; ky++) {
    int ih = ph + ky - 1;
    if (ih < 0 || ih > 31) continue;
#pragma unroll
    for (int kx = 0; kx < 3; kx++) {
      int iw = pw + kx - 1;
      if (iw < 0 || iw > 31) continue;
      acc = fmaf(wp[ky * 3 + kx], ip[ih * 32 + iw], acc);
    }
  }
  out[t] = acc;
}

// ---------------------------------------------------------------
// grouped 3x3 (groups=128, 2-in 2-out per group) on kv1 (B,256,32,32)
// o < 128 -> k  (layout (B,128,1024): (b, h*32+d, n))
// o >= 128 -> v (layout (B,H,N,D):    vnd[((b*4+h)*1024+n)*32+d])
__global__ void k_kv2(const float* __restrict__ in, const float* __restrict__ wt,
                      const float* __restrict__ bias, float* __restrict__ kout,
                      float* __restrict__ vnd) {
  int t = blockIdx.x * 256 + threadIdx.x;
  if (t >= NB * 256 * NTOK) return;
  int p = t & 1023;
  int pw = p & 31, ph = p >> 5;
  int bo = t >> 10;
  int o = bo & 255;
  int b = bo >> 8;
  int g = o >> 1;
  const float* ip0 = in + ((size_t)b * 256 + 2 * g) * NTOK;
  const float* ip1 = ip0 + NTOK;
  const float* wp = wt + o * 18; // [2][3][3]
  float acc = bias[o];
#pragma unroll
  for (int ky = 0; ky < 3; ky++) {
    int ih = ph + ky - 1;
    if (ih < 0 || ih > 31) continue;
#pragma unroll
    for (int kx = 0; kx < 3; kx++) {
      int iw = pw + kx - 1;
      if (iw < 0 || iw > 31) continue;
      float w0 = wp[ky * 3 + kx];
      float w1 = wp[9 + ky * 3 + kx];
      acc = fmaf(w0, ip0[ih * 32 + iw], acc);
      acc = fmaf(w1, ip1[ih * 32 + iw], acc);
    }
  }
  if (o < 128) {
    kout[((size_t)b * NC + o) * NTOK + p] = acc;
  } else {
    int c = o - 128;
    int h = c >> 5, d = c & 31;
    vnd[(((size_t)b * HEADS + h) * NTOK + p) * HDIM + d] = acc;
  }
}

// ---------------------------------------------------------------
// attention: per query row -> 1024 logits -> top32 -> softmax -> weighted V sum
// grid: 256 blocks = (8 chunks) x (4 heads) x (8 batch); block = 512 threads (8 waves)
// each wave handles 16 rows. K slice (32 x 1024 f32 = 128KB) staged in LDS.
__launch_bounds__(512, 1)
__global__ void k_attn(const float* __restrict__ qbuf, const float* __restrict__ kbuf,
                       const float* __restrict__ vnd, const float* __restrict__ rel,
                       const float* __restrict__ temp, float* __restrict__ att) {
  __shared__ __align__(16) float k_lds[32 * 1024];

  int bid = blockIdx.x;
  int chunk = bid & 7;
  int h = (bid >> 3) & 3;
  int b = bid >> 5;
  int tid = threadIdx.x;
  int lane = tid & 63;
  int wave = tid >> 6;

  // stage K (d-major: k_lds[d][n]) -- global layout is already (b, h*32+d, n)
  const float4* kg4 = (const float4*)(kbuf + ((size_t)b * NC + h * 32) * NTOK);
  float4* kl4 = (float4*)k_lds;
  for (int i = tid; i < 32 * 1024 / 4; i += 512) kl4[i] = kg4[i];
  __syncthreads();

  float tmpr = temp[h];
  const float* vrow = vnd + ((size_t)b * HEADS + h) * NTOK * HDIM;

  for (int r = 0; r < 16; r++) {
    int qi = chunk * 128 + wave * 16 + r;
    const float* qrow = qbuf + ((size_t)b * NC + h * 32) * NTOK + qi;

    // ---- logits: dot(q, k_j) over d=0..31, j = i*256 + lane*4 + m ----
    float acc[16];
#pragma unroll
    for (int i = 0; i < 16; i++) acc[i] = 0.f;
#pragma unroll
    for (int d = 0; d < 32; d++) {
      float qd = qrow[d * NTOK];
#pragma unroll
      for (int i = 0; i < 4; i++) {
        float4 kv = *(const float4*)&k_lds[d * 1024 + i * 256 + lane * 4];
        acc[i * 4 + 0] = fmaf(qd, kv.x, acc[i * 4 + 0]);
        acc[i * 4 + 1] = fmaf(qd, kv.y, acc[i * 4 + 1]);
        acc[i * 4 + 2] = fmaf(qd, kv.z, acc[i * 4 + 2]);
        acc[i * 4 + 3] = fmaf(qd, kv.w, acc[i * 4 + 3]);
      }
    }
    float val[16];
    int idx[16];
    const float4* relp = (const float4*)(rel + (((size_t)b * HEADS + h) * NTOK + qi) * NTOK);
#pragma unroll
    for (int i = 0; i < 4; i++) {
      float4 rv = relp[i * 64 + lane];
      val[i * 4 + 0] = fmaf(tmpr, acc[i * 4 + 0], rv.x);
      val[i * 4 + 1] = fmaf(tmpr, acc[i * 4 + 1], rv.y);
      val[i * 4 + 2] = fmaf(tmpr, acc[i * 4 + 2], rv.z);
      val[i * 4 + 3] = fmaf(tmpr, acc[i * 4 + 3], rv.w);
      idx[i * 4 + 0] = i * 256 + lane * 4 + 0;
      idx[i * 4 + 1] = i * 256 + lane * 4 + 1;
      idx[i * 4 + 2] = i * 256 + lane * 4 + 2;
      idx[i * 4 + 3] = i * 256 + lane * 4 + 3;
    }

    // ---- per-lane bitonic sort of 16 (descending), static-index network ----
#pragma unroll
    for (int k = 2; k <= 16; k <<= 1) {
#pragma unroll
      for (int j = k >> 1; j > 0; j >>= 1) {
#pragma unroll
        for (int i = 0; i < 16; i++) {
          int ixj = i ^ j;
          if (ixj > i) {
            bool sw = ((i & k) == 0) ? (val[i] < val[ixj]) : (val[i] > val[ixj]);
            if (sw) {
              float tv = val[i]; val[i] = val[ixj]; val[ixj] = tv;
              int ti = idx[i]; idx[i] = idx[ixj]; idx[ixj] = ti;
            }
          }
        }
      }
    }

    // ---- 32-way merge select + online softmax + V accumulation ----
    float m = 0.f, sumexp = 0.f, oacc = 0.f;
#pragma unroll 1
    for (int t2 = 0; t2 < TOPK; t2++) {
      float mx = val[0];
#pragma unroll
      for (int off = 32; off >= 1; off >>= 1) mx = fmaxf(mx, __shfl_xor(mx, off));
      unsigned long long ball = __ballot(val[0] == mx);
      int winner = (int)__builtin_ctzll(ball);
      int widx = __shfl(idx[0], winner);
      if (t2 == 0) m = mx;
      float e = __expf(mx - m);
      sumexp += e;
      if (lane < HDIM) oacc = fmaf(e, vrow[widx * HDIM + lane], oacc);
      if (lane == winner) {
#pragma unroll
        for (int i = 0; i < 15; i++) { val[i] = val[i + 1]; idx[i] = idx[i + 1]; }
        val[15] = -3.0e38f;
      }
    }
    if (lane < HDIM) {
      att[((size_t)b * NC + h * 32 + lane) * NTOK + qi] = oacc / sumexp;
    }
  }
}

// ---------------------------------------------------------------
// bilinear 2x upsample weights (jax scale_and_translate semantics, edge-renormalized)
__device__ __forceinline__ void bil(int i, int& j0, int& j1, float& wa, float& wb) {
  if (i & 1) {
    j0 = i >> 1; j1 = j0 + 1; wa = 0.75f; wb = 0.25f;
    if (j1 > 31) { j1 = 31; wa = 1.f; wb = 0.f; }
  } else {
    j0 = (i >> 1) - 1; j1 = j0 + 1; wa = 0.25f; wb = 0.75f;
    if (j0 < 0) { j0 = 0; wa = 0.f; wb = 1.f; }
  }
}

// mid = lepe(x) + upsample(att) ; (B,128,64,64)
__global__ void k_mid(const float* __restrict__ x, const float* __restrict__ lepe_w,
                      const float* __restrict__ lepe_b, const float* __restrict__ att,
                      float* __restrict__ mid) {
  int t = blockIdx.x * 256 + threadIdx.x;
  if (t >= NB * NC * NH * NW) return;
  int w = t & 63;
  int h0 = (t >> 6) & 63;
  int bc = t >> 12;
  int c = bc & 127;
  const float* xp = x + (size_t)bc * (NH * NW);
  const float* wp = lepe_w + c * 25;
  float acc = lepe_b[c];
#pragma unroll
  for (int ky = 0; ky < 5; ky++) {
    int ih = h0 + ky - 2;
    if (ih < 0 || ih > 63) continue;
#pragma unroll
    for (int kx = 0; kx < 5; kx++) {
      int iw = w + kx - 2;
      if (iw < 0 || iw > 63) continue;
      acc = fmaf(wp[ky * 5 + kx], xp[ih * 64 + iw], acc);
    }
  }
  int jh0, jh1, jw0, jw1;
  float wha, whb, wwa, wwb;
  bil(h0, jh0, jh1, wha, whb);
  bil(w, jw0, jw1, wwa, wwb);
  const float* ap = att + (size_t)bc * NTOK;
  float up = wha * (wwa * ap[jh0 * 32 + jw0] + wwb * ap[jh0 * 32 + jw1]) +
             whb * (wwa * ap[jh1 * 32 + jw0] + wwb * ap[jh1 * 32 + jw1]);
  mid[t] = acc + up;
}

// ---------------------------------------------------------------
// final 1x1 conv: out[b][co][p] = b[co] + sum_ci w[co][ci] * mid[b][ci][p]
__global__ void k_final(const float* __restrict__ mid, const float* __restrict__ wt,
                        const float* __restrict__ bias, float* __restrict__ out) {
  int t = blockIdx.x * 256 + threadIdx.x;
  int p = t & 4095;
  int rest = t >> 12;
  int cg = rest & 15;
  int b = rest >> 4;
  if (b >= NB) return;
  const float* mp = mid + (size_t)b * NC * (NH * NW) + p;
  float acc[8];
#pragma unroll
  for (int i = 0; i < 8; i++) acc[i] = bias[cg * 8 + i];
  for (int ci = 0; ci < NC; ci++) {
    float mv = mp[ci * 4096];
#pragma unroll
    for (int i = 0; i < 8; i++) acc[i] = fmaf(wt[(cg * 8 + i) * NC + ci], mv, acc[i]);
  }
#pragma unroll
  for (int i = 0; i < 8; i++) out[((size_t)b * NC + cg * 8 + i) * 4096 + p] = acc[i];
}

// ---------------------------------------------------------------
extern "C" void kernel_launch(void* const* d_in, const int* in_sizes, int n_in,
                              void* d_out, int out_size, void* d_ws, size_t ws_size,
                              hipStream_t stream) {
  const float* x      = (const float*)d_in[0];
  const float* y      = (const float*)d_in[1];
  const float* rel    = (const float*)d_in[2];
  const float* q1_w   = (const float*)d_in[3];
  const float* q1_b   = (const float*)d_in[4];
  const float* q2_w   = (const float*)d_in[5];
  const float* q2_b   = (const float*)d_in[6];
  const float* kv1_w  = (const float*)d_in[7];
  const float* kv1_b  = (const float*)d_in[8];
  const float* kv2_w  = (const float*)d_in[9];
  const float* kv2_b  = (const float*)d_in[10];
  const float* lepe_w = (const float*)d_in[11];
  const float* lepe_b = (const float*)d_in[12];
  const float* out_w  = (const float*)d_in[13];
  const float* out_b  = (const float*)d_in[14];
  const float* temp   = (const float*)d_in[15];
  float* out = (float*)d_out;

  float* ws = (float*)d_ws;
  const size_t SP = (size_t)NB * NC * NTOK;   // 1,048,576
  float* xp     = ws;                  // SP
  float* yp     = xp + SP;             // SP
  float* q1buf  = yp + SP;             // SP
  float* kv1buf = q1buf + SP;          // 2*SP
  float* qbuf   = kv1buf + 2 * SP;     // SP
  float* kbuf   = qbuf + SP;           // SP
  float* vnd    = kbuf + SP;           // SP
  float* attb   = vnd + SP;            // SP
  float* mid    = attb + SP;           // 4*SP

  // pool x,y
  k_pool<<<8192, 256, 0, stream>>>(x, y, xp, yp);
  // q path
  k_conv1x1<128><<<512, 256, 0, stream>>>(xp, q1_w, q1_b, q1buf);
  k_dw3<<<4096, 256, 0, stream>>>(q1buf, q2_w, q2_b, qbuf);
  // kv path
  k_conv1x1<256><<<1024, 256, 0, stream>>>(yp, kv1_w, kv1_b, kv1buf);
  k_kv2<<<8192, 256, 0, stream>>>(kv1buf, kv2_w, kv2_b, kbuf, vnd);
  // attention
  k_attn<<<256, 512, 0, stream>>>(qbuf, kbuf, vnd, rel, temp, attb);
  // lepe + upsample
  k_mid<<<16384, 256, 0, stream>>>(x, lepe_w, lepe_b, attb, mid);
  // final 1x1
  k_final<<<2048, 256, 0, stream>>>(mid, out_w, out_b, out);
}

// Round 2
// 426.081 us; speedup vs baseline: 2.2198x; 2.2198x over previous
//
#include <hip/hip_runtime.h>

// Problem constants
#define NB 8
#define NC 128
#define NH 64
#define NW 64
#define HEADS 4
#define HP 32
#define WP 32
#define NTOK 1024     // HP*WP
#define TOPK 32
#define HDIM 32

// ---------------------------------------------------------------
// bf16 helpers (round-to-nearest-even)
__device__ __forceinline__ unsigned bf16r(float f) {
  unsigned u = __float_as_uint(f);
  return (u + 0x7FFFu + ((u >> 16) & 1u)) >> 16;
}
__device__ __forceinline__ unsigned packbf(float a, float b) {
  return bf16r(a) | (bf16r(b) << 16);
}

// DPP wave64 max-reduce; result broadcast via readlane(63)
#define DPP_MAXSTEP(v, ctrl) \
  v = fmaxf(v, __int_as_float(__builtin_amdgcn_update_dpp(0, __float_as_int(v), ctrl, 0xF, 0xF, true)))

__device__ __forceinline__ float wave_max64(float v) {
  DPP_MAXSTEP(v, 0xB1);   // quad_perm [1,0,3,2]  (xor 1)
  DPP_MAXSTEP(v, 0x4E);   // quad_perm [2,3,0,1]  (xor 2)
  DPP_MAXSTEP(v, 0x141);  // row_half_mirror      (xor 4)
  DPP_MAXSTEP(v, 0x140);  // row_mirror           (xor 8)
  DPP_MAXSTEP(v, 0x142);  // row_bcast:15
  DPP_MAXSTEP(v, 0x143);  // row_bcast:31  -> lane 63 holds full max
  return __int_as_float(__builtin_amdgcn_readlane(__float_as_int(v), 63));
}

// ---------------------------------------------------------------
// avg pool 2x2 on x and y
__global__ void k_pool(const float* __restrict__ x, const float* __restrict__ y,
                       float* __restrict__ xp, float* __restrict__ yp) {
  int idx = blockIdx.x * 256 + threadIdx.x;
  const int total = NB * NC * HP * WP; // 1,048,576
  if (idx >= 2 * total) return;
  bool isY = idx >= total;
  int i = isY ? idx - total : idx;
  int pw = i & 31, ph = (i >> 5) & 31, bc = i >> 10;
  const float* src = (isY ? y : x) + ((size_t)bc * 64 + ph * 2) * 64 + pw * 2;
  float v = 0.25f * (src[0] + src[1] + src[64] + src[65]);
  (isY ? yp : xp)[i] = v;
}

// ---------------------------------------------------------------
// 1x1 conv
template <int CO>
__global__ void k_conv1x1(const float* __restrict__ in, const float* __restrict__ wt,
                          const float* __restrict__ bias, float* __restrict__ out) {
  int t = blockIdx.x * 256 + threadIdx.x;
  const int CG = CO / 8;
  int p = t & 1023;
  int rest = t >> 10;
  int cg = rest % CG;
  int b = rest / CG;
  if (b >= NB) return;
  const float* ip = in + (size_t)b * NC * NTOK + p;
  float acc[8];
#pragma unroll
  for (int i = 0; i < 8; i++) acc[i] = bias[cg * 8 + i];
  for (int ci = 0; ci < NC; ci++) {
    float mv = ip[ci * NTOK];
#pragma unroll
    for (int i = 0; i < 8; i++) acc[i] = fmaf(wt[(cg * 8 + i) * NC + ci], mv, acc[i]);
  }
#pragma unroll
  for (int i = 0; i < 8; i++) out[((size_t)b * CO + cg * 8 + i) * NTOK + p] = acc[i];
}

// ---------------------------------------------------------------
// depthwise 3x3 pad=1 on (B,128,32,32)
__global__ void k_dw3(const float* __restrict__ in, const float* __restrict__ wt,
                      const float* __restrict__ bias, float* __restrict__ out) {
  int t = blockIdx.x * 256 + threadIdx.x;
  if (t >= NB * NC * NTOK) return;
  int p = t & 1023;
  int pw = p & 31, ph = p >> 5;
  int bc = t >> 10;
  int c = bc & 127;
  const float* ip = in + (size_t)bc * NTOK;
  const float* wp = wt + c * 9;
  float acc = bias[c];
#pragma unroll
  for (int ky = 0; ky < 3; ky++) {
    int ih = ph + ky - 1;
    if (ih < 0 || ih > 31) continue;
#pragma unroll
    for (int kx = 0; kx < 3; kx++) {
      int iw = pw + kx - 1;
      if (iw < 0 || iw > 31) continue;
      acc = fmaf(wp[ky * 3 + kx], ip[ih * 32 + iw], acc);
    }
  }
  out[t] = acc;
}

// ---------------------------------------------------------------
// grouped 3x3 (groups=128) on kv1 (B,256,32,32)
__global__ void k_kv2(const float* __restrict__ in, const float* __restrict__ wt,
                      const float* __restrict__ bias, float* __restrict__ kout,
                      float* __restrict__ vnd) {
  int t = blockIdx.x * 256 + threadIdx.x;
  if (t >= NB * 256 * NTOK) return;
  int p = t & 1023;
  int pw = p & 31, ph = p >> 5;
  int bo = t >> 10;
  int o = bo & 255;
  int b = bo >> 8;
  int g = o >> 1;
  const float* ip0 = in + ((size_t)b * 256 + 2 * g) * NTOK;
  const float* ip1 = ip0 + NTOK;
  const float* wp = wt + o * 18; // [2][3][3]
  float acc = bias[o];
#pragma unroll
  for (int ky = 0; ky < 3; ky++) {
    int ih = ph + ky - 1;
    if (ih < 0 || ih > 31) continue;
#pragma unroll
    for (int kx = 0; kx < 3; kx++) {
      int iw = pw + kx - 1;
      if (iw < 0 || iw > 31) continue;
      float w0 = wp[ky * 3 + kx];
      float w1 = wp[9 + ky * 3 + kx];
      acc = fmaf(w0, ip0[ih * 32 + iw], acc);
      acc = fmaf(w1, ip1[ih * 32 + iw], acc);
    }
  }
  if (o < 128) {
    kout[((size_t)b * NC + o) * NTOK + p] = acc;
  } else {
    int c = o - 128;
    int h = c >> 5, d = c & 31;
    vnd[(((size_t)b * HEADS + h) * NTOK + p) * HDIM + d] = acc;
  }
}

// ---------------------------------------------------------------
// attention v2: bf16 K+V in LDS, 4-row logit passes, DPP-based top-32 select
// grid: 256 blocks = (8 chunks) x (4 heads) x (8 batch); block = 512 (8 waves)
__device__ __forceinline__ void extract_one(float (&vr)[16], unsigned& c0, unsigned& c1,
                                            int lane, float& mx, int& gidx) {
  mx = wave_max64(vr[0]);
  unsigned long long bl = __ballot(vr[0] == mx);
  int w = (int)__builtin_ctzll(bl);
  int hc = (int)(c0 & 15u);
  int wc = __builtin_amdgcn_readlane(hc, w);
  gidx = ((wc >> 2) << 8) + (w << 2) + (wc & 3);
  if (lane == w) {
#pragma unroll
    for (int s = 0; s < 15; s++) vr[s] = vr[s + 1];
    vr[15] = -3.0e38f;
    c0 = (c0 >> 4) | (c1 << 28);
    c1 >>= 4;
  }
}

__device__ __forceinline__ float vload_bf(const unsigned* vsh, int gidx, int lane) {
  unsigned w = vsh[(gidx << 4) + (lane >> 1)];
  return __uint_as_float((lane & 1) ? (w & 0xFFFF0000u) : (w << 16));
}

__launch_bounds__(512, 2)
__global__ void k_attn(const float* __restrict__ qbuf, const float* __restrict__ kbuf,
                       const float* __restrict__ vnd, const float* __restrict__ rel,
                       const float* __restrict__ temp, float* __restrict__ att) {
  __shared__ __align__(16) unsigned ksh[16384];  // bf16 K [d][n], 64KB
  __shared__ __align__(16) unsigned vsh[16384];  // bf16 V [n][d], 64KB

  int bid = blockIdx.x;
  int chunk = bid & 7;
  int h = (bid >> 3) & 3;
  int b = bid >> 5;
  int tid = threadIdx.x;
  int lane = tid & 63;
  int wave = tid >> 6;

  const float4* kg4 = (const float4*)(kbuf + ((size_t)b * NC + h * HDIM) * NTOK);
  const float4* vg4 = (const float4*)(vnd + ((size_t)(b * HEADS + h)) * NTOK * HDIM);
  uint2* k2w = (uint2*)ksh;
  uint2* v2w = (uint2*)vsh;
  for (int i = tid; i < 8192; i += 512) {
    float4 f = kg4[i];
    k2w[i] = make_uint2(packbf(f.x, f.y), packbf(f.z, f.w));
    float4 g = vg4[i];
    v2w[i] = make_uint2(packbf(g.x, g.y), packbf(g.z, g.w));
  }
  __syncthreads();

  const float tmpr = temp[h];
  const uint2* k2 = (const uint2*)ksh;

#pragma unroll 1
  for (int pass = 0; pass < 4; pass++) {
    int qbase = chunk * 128 + wave * 16 + pass * 4;

    float acc[4][16];
#pragma unroll
    for (int r = 0; r < 4; r++)
#pragma unroll
      for (int j = 0; j < 16; j++) acc[r][j] = 0.f;

    // prefetch rel rows (global, coalesced)
    float4 rv[4][4];
    {
      const float4* relp = (const float4*)(rel + (((size_t)b * HEADS + h) * NTOK + qbase) * NTOK);
#pragma unroll
      for (int r = 0; r < 4; r++)
#pragma unroll
        for (int i = 0; i < 4; i++) rv[r][i] = relp[r * 256 + i * 64 + lane];
    }

    // logits for 4 rows, bf16 K from LDS shared across rows
    const float* q0 = qbuf + ((size_t)b * NC + h * HDIM) * NTOK + qbase;
#pragma unroll 8
    for (int d = 0; d < 32; d++) {
      float qd[4];
#pragma unroll
      for (int r = 0; r < 4; r++) qd[r] = q0[d * NTOK + r];
#pragma unroll
      for (int i = 0; i < 4; i++) {
        uint2 kw = k2[d * 256 + i * 64 + lane];
        float k0 = __uint_as_float(kw.x << 16);
        float k1 = __uint_as_float(kw.x & 0xFFFF0000u);
        float k2v = __uint_as_float(kw.y << 16);
        float k3 = __uint_as_float(kw.y & 0xFFFF0000u);
#pragma unroll
        for (int r = 0; r < 4; r++) {
          acc[r][i * 4 + 0] = fmaf(qd[r], k0, acc[r][i * 4 + 0]);
          acc[r][i * 4 + 1] = fmaf(qd[r], k1, acc[r][i * 4 + 1]);
          acc[r][i * 4 + 2] = fmaf(qd[r], k2v, acc[r][i * 4 + 2]);
          acc[r][i * 4 + 3] = fmaf(qd[r], k3, acc[r][i * 4 + 3]);
        }
      }
    }

    // finalize logits (temp * qk + rel), per-lane bitonic sort 16 with 4-bit codes
    unsigned cp0[4], cp1[4];
#pragma unroll
    for (int r = 0; r < 4; r++) {
#pragma unroll
      for (int i = 0; i < 4; i++) {
        acc[r][i * 4 + 0] = fmaf(tmpr, acc[r][i * 4 + 0], rv[r][i].x);
        acc[r][i * 4 + 1] = fmaf(tmpr, acc[r][i * 4 + 1], rv[r][i].y);
        acc[r][i * 4 + 2] = fmaf(tmpr, acc[r][i * 4 + 2], rv[r][i].z);
        acc[r][i * 4 + 3] = fmaf(tmpr, acc[r][i * 4 + 3], rv[r][i].w);
      }
      int code[16];
#pragma unroll
      for (int s = 0; s < 16; s++) code[s] = s;
#pragma unroll
      for (int k = 2; k <= 16; k <<= 1) {
#pragma unroll
        for (int j = k >> 1; j > 0; j >>= 1) {
#pragma unroll
          for (int i = 0; i < 16; i++) {
            int ixj = i ^ j;
            if (ixj > i) {
              bool sw = ((i & k) == 0) ? (acc[r][i] < acc[r][ixj]) : (acc[r][i] > acc[r][ixj]);
              if (sw) {
                float tv = acc[r][i]; acc[r][i] = acc[r][ixj]; acc[r][ixj] = tv;
                int tc = code[i]; code[i] = code[ixj]; code[ixj] = tc;
              }
            }
          }
        }
      }
      unsigned p0 = 0, p1 = 0;
#pragma unroll
      for (int s = 0; s < 8; s++) {
        p0 |= ((unsigned)code[s]) << (4 * s);
        p1 |= ((unsigned)code[s + 8]) << (4 * s);
      }
      cp0[r] = p0; cp1[r] = p1;
    }

    // interleaved 4-row top-32 select + online softmax + V (LDS bf16)
    float mrow[4], se[4], oac[4];
#pragma unroll
    for (int r = 0; r < 4; r++) {
      float mx; int gi;
      extract_one(acc[r], cp0[r], cp1[r], lane, mx, gi);
      mrow[r] = mx;
      se[r] = 1.f;
      float vv = 0.f;
      if (lane < HDIM) vv = vload_bf(vsh, gi, lane);
      oac[r] = vv;
    }
#pragma unroll 1
    for (int t2 = 1; t2 < TOPK; t2++) {
#pragma unroll
      for (int r = 0; r < 4; r++) {
        float mx; int gi;
        extract_one(acc[r], cp0[r], cp1[r], lane, mx, gi);
        float e = __expf(mx - mrow[r]);
        se[r] += e;
        float vv = 0.f;
        if (lane < HDIM) vv = vload_bf(vsh, gi, lane);
        oac[r] = fmaf(e, vv, oac[r]);
      }
    }

#pragma unroll
    for (int r = 0; r < 4; r++) {
      if (lane < HDIM) {
        att[((size_t)b * NC + h * HDIM + lane) * NTOK + (qbase + r)] = oac[r] / se[r];
      }
    }
  }
}

// ---------------------------------------------------------------
// bilinear 2x upsample weights (jax scale_and_translate semantics)
__device__ __forceinline__ void bil(int i, int& j0, int& j1, float& wa, float& wb) {
  if (i & 1) {
    j0 = i >> 1; j1 = j0 + 1; wa = 0.75f; wb = 0.25f;
    if (j1 > 31) { j1 = 31; wa = 1.f; wb = 0.f; }
  } else {
    j0 = (i >> 1) - 1; j1 = j0 + 1; wa = 0.25f; wb = 0.75f;
    if (j0 < 0) { j0 = 0; wa = 0.f; wb = 1.f; }
  }
}

// mid = lepe(x) + upsample(att) ; (B,128,64,64)
__global__ void k_mid(const float* __restrict__ x, const float* __restrict__ lepe_w,
                      const float* __restrict__ lepe_b, const float* __restrict__ att,
                      float* __restrict__ mid) {
  int t = blockIdx.x * 256 + threadIdx.x;
  if (t >= NB * NC * NH * NW) return;
  int w = t & 63;
  int h0 = (t >> 6) & 63;
  int bc = t >> 12;
  int c = bc & 127;
  const float* xp = x + (size_t)bc * (NH * NW);
  const float* wp = lepe_w + c * 25;
  float acc = lepe_b[c];
#pragma unroll
  for (int ky = 0; ky < 5; ky++) {
    int ih = h0 + ky - 2;
    if (ih < 0 || ih > 63) continue;
#pragma unroll
    for (int kx = 0; kx < 5; kx++) {
      int iw = w + kx - 2;
      if (iw < 0 || iw > 63) continue;
      acc = fmaf(wp[ky * 5 + kx], xp[ih * 64 + iw], acc);
    }
  }
  int jh0, jh1, jw0, jw1;
  float wha, whb, wwa, wwb;
  bil(h0, jh0, jh1, wha, whb);
  bil(w, jw0, jw1, wwa, wwb);
  const float* ap = att + (size_t)bc * NTOK;
  float up = wha * (wwa * ap[jh0 * 32 + jw0] + wwb * ap[jh0 * 32 + jw1]) +
             whb * (wwa * ap[jh1 * 32 + jw0] + wwb * ap[jh1 * 32 + jw1]);
  mid[t] = acc + up;
}

// ---------------------------------------------------------------
// final 1x1 conv
__global__ void k_final(const float* __restrict__ mid, const float* __restrict__ wt,
                        const float* __restrict__ bias, float* __restrict__ out) {
  int t = blockIdx.x * 256 + threadIdx.x;
  int p = t & 4095;
  int rest = t >> 12;
  int cg = rest & 15;
  int b = rest >> 4;
  if (b >= NB) return;
  const float* mp = mid + (size_t)b * NC * (NH * NW) + p;
  float acc[8];
#pragma unroll
  for (int i = 0; i < 8; i++) acc[i] = bias[cg * 8 + i];
  for (int ci = 0; ci < NC; ci++) {
    float mv = mp[ci * 4096];
#pragma unroll
    for (int i = 0; i < 8; i++) acc[i] = fmaf(wt[(cg * 8 + i) * NC + ci], mv, acc[i]);
  }
#pragma unroll
  for (int i = 0; i < 8; i++) out[((size_t)b * NC + cg * 8 + i) * 4096 + p] = acc[i];
}

// ---------------------------------------------------------------
extern "C" void kernel_launch(void* const* d_in, const int* in_sizes, int n_in,
                              void* d_out, int out_size, void* d_ws, size_t ws_size,
                              hipStream_t stream) {
  const float* x      = (const float*)d_in[0];
  const float* y      = (const float*)d_in[1];
  const float* rel    = (const float*)d_in[2];
  const float* q1_w   = (const float*)d_in[3];
  const float* q1_b   = (const float*)d_in[4];
  const float* q2_w   = (const float*)d_in[5];
  const float* q2_b   = (const float*)d_in[6];
  const float* kv1_w  = (const float*)d_in[7];
  const float* kv1_b  = (const float*)d_in[8];
  const float* kv2_w  = (const float*)d_in[9];
  const float* kv2_b  = (const float*)d_in[10];
  const float* lepe_w = (const float*)d_in[11];
  const float* lepe_b = (const float*)d_in[12];
  const float* out_w  = (const float*)d_in[13];
  const float* out_b  = (const float*)d_in[14];
  const float* temp   = (const float*)d_in[15];
  float* out = (float*)d_out;

  float* ws = (float*)d_ws;
  const size_t SP = (size_t)NB * NC * NTOK;   // 1,048,576
  float* xp     = ws;                  // SP
  float* yp     = xp + SP;             // SP
  float* q1buf  = yp + SP;             // SP
  float* kv1buf = q1buf + SP;          // 2*SP
  float* qbuf   = kv1buf + 2 * SP;     // SP
  float* kbuf   = qbuf + SP;           // SP
  float* vnd    = kbuf + SP;           // SP
  float* attb   = vnd + SP;            // SP
  float* mid    = attb + SP;           // 4*SP

  k_pool<<<8192, 256, 0, stream>>>(x, y, xp, yp);
  k_conv1x1<128><<<512, 256, 0, stream>>>(xp, q1_w, q1_b, q1buf);
  k_dw3<<<4096, 256, 0, stream>>>(q1buf, q2_w, q2_b, qbuf);
  k_conv1x1<256><<<1024, 256, 0, stream>>>(yp, kv1_w, kv1_b, kv1buf);
  k_kv2<<<8192, 256, 0, stream>>>(kv1buf, kv2_w, kv2_b, kbuf, vnd);
  k_attn<<<256, 512, 0, stream>>>(qbuf, kbuf, vnd, rel, temp, attb);
  k_mid<<<16384, 256, 0, stream>>>(x, lepe_w, lepe_b, attb, mid);
  k_final<<<2048, 256, 0, stream>>>(mid, out_w, out_b, out);
}

// Round 4
// 356.051 us; speedup vs baseline: 2.6565x; 1.1967x over previous
//
#include <hip/hip_runtime.h>

// Problem constants
#define NB 8
#define NC 128
#define NH 64
#define NW 64
#define HEADS 4
#define HP 32
#define WP 32
#define NTOK 1024     // HP*WP
#define TOPK 32
#define HDIM 32

typedef float v2f __attribute__((ext_vector_type(2)));

// ---------------------------------------------------------------
// bf16 helpers (round-to-nearest-even)
__device__ __forceinline__ unsigned bf16r(float f) {
  unsigned u = __float_as_uint(f);
  return (u + 0x7FFFu + ((u >> 16) & 1u)) >> 16;
}

// monotone float->uint map (order-preserving)
__device__ __forceinline__ unsigned fmap(float f) {
  unsigned u = __float_as_uint(f);
  return u ^ ((unsigned)((int)u >> 31) | 0x80000000u);
}

__device__ __forceinline__ v2f bfpair(unsigned w) {
  v2f r;
  r.x = __uint_as_float(w << 16);
  r.y = __uint_as_float(w & 0xFFFF0000u);
  return r;
}

// DPP wave64 max-reduce on unsigned; result broadcast via readlane(63)
__device__ __forceinline__ unsigned wave_maxu(unsigned v) {
#define ST(ctrl)                                                                     \
  {                                                                                  \
    unsigned o = (unsigned)__builtin_amdgcn_update_dpp(0, (int)v, ctrl, 0xF, 0xF, true); \
    v = v > o ? v : o;                                                               \
  }
  ST(0xB1)   // quad_perm [1,0,3,2]
  ST(0x4E)   // quad_perm [2,3,0,1]
  ST(0x141)  // row_half_mirror
  ST(0x140)  // row_mirror
  ST(0x142)  // row_bcast:15
  ST(0x143)  // row_bcast:31
#undef ST
  return (unsigned)__builtin_amdgcn_readlane((int)v, 63);
}

// ---------------------------------------------------------------
// avg pool 2x2 on x and y
__global__ void k_pool(const float* __restrict__ x, const float* __restrict__ y,
                       float* __restrict__ xp, float* __restrict__ yp) {
  int idx = blockIdx.x * 256 + threadIdx.x;
  const int total = NB * NC * HP * WP; // 1,048,576
  if (idx >= 2 * total) return;
  bool isY = idx >= total;
  int i = isY ? idx - total : idx;
  int pw = i & 31, ph = (i >> 5) & 31, bc = i >> 10;
  const float* src = (isY ? y : x) + ((size_t)bc * 64 + ph * 2) * 64 + pw * 2;
  float v = 0.25f * (src[0] + src[1] + src[64] + src[65]);
  (isY ? yp : xp)[i] = v;
}

// ---------------------------------------------------------------
// 1x1 conv, 16 outputs per thread (weights wave-uniform -> s_loads)
template <int CO>
__global__ void k_conv1x1(const float* __restrict__ in, const float* __restrict__ wt,
                          const float* __restrict__ bias, float* __restrict__ out) {
  const int CG = CO / 16;
  int p = (blockIdx.x & 3) * 256 + threadIdx.x;
  int rest = blockIdx.x >> 2;
  int cg = rest % CG;
  int b = rest / CG;
  if (b >= NB) return;
  const float* ip = in + (size_t)b * NC * NTOK + p;
  const float* wp = wt + cg * 16 * NC;
  float acc[16];
#pragma unroll
  for (int i = 0; i < 16; i++) acc[i] = bias[cg * 16 + i];
  for (int ci = 0; ci < NC; ci++) {
    float mv = ip[ci * NTOK];
#pragma unroll
    for (int i = 0; i < 16; i++) acc[i] = fmaf(wp[i * NC + ci], mv, acc[i]);
  }
#pragma unroll
  for (int i = 0; i < 16; i++) out[((size_t)b * CO + cg * 16 + i) * NTOK + p] = acc[i];
}

// ---------------------------------------------------------------
// depthwise 3x3 pad=1 on (B,128,32,32)
__global__ void k_dw3(const float* __restrict__ in, const float* __restrict__ wt,
                      const float* __restrict__ bias, float* __restrict__ out) {
  int t = blockIdx.x * 256 + threadIdx.x;
  if (t >= NB * NC * NTOK) return;
  int p = t & 1023;
  int pw = p & 31, ph = p >> 5;
  int bc = t >> 10;
  int c = bc & 127;
  const float* ip = in + (size_t)bc * NTOK;
  const float* wp = wt + c * 9;
  float acc = bias[c];
#pragma unroll
  for (int ky = 0; ky < 3; ky++) {
    int ih = ph + ky - 1;
    if (ih < 0 || ih > 31) continue;
#pragma unroll
    for (int kx = 0; kx < 3; kx++) {
      int iw = pw + kx - 1;
      if (iw < 0 || iw > 31) continue;
      acc = fmaf(wp[ky * 3 + kx], ip[ih * 32 + iw], acc);
    }
  }
  out[t] = acc;
}

// ---------------------------------------------------------------
// grouped 3x3 (groups=128) on kv1 (B,256,32,32); emits bf16 K and bf16 V
__global__ void k_kv2(const float* __restrict__ in, const float* __restrict__ wt,
                      const float* __restrict__ bias, unsigned short* __restrict__ kbf,
                      unsigned short* __restrict__ vbf) {
  int t = blockIdx.x * 256 + threadIdx.x;
  if (t >= NB * 256 * NTOK) return;
  int p = t & 1023;
  int pw = p & 31, ph = p >> 5;
  int bo = t >> 10;
  int o = bo & 255;
  int b = bo >> 8;
  int g = o >> 1;
  const float* ip0 = in + ((size_t)b * 256 + 2 * g) * NTOK;
  const float* ip1 = ip0 + NTOK;
  const float* wp = wt + o * 18; // [2][3][3]
  float acc = bias[o];
#pragma unroll
  for (int ky = 0; ky < 3; ky++) {
    int ih = ph + ky - 1;
    if (ih < 0 || ih > 31) continue;
#pragma unroll
    for (int kx = 0; kx < 3; kx++) {
      int iw = pw + kx - 1;
      if (iw < 0 || iw > 31) continue;
      float w0 = wp[ky * 3 + kx];
      float w1 = wp[9 + ky * 3 + kx];
      acc = fmaf(w0, ip0[ih * 32 + iw], acc);
      acc = fmaf(w1, ip1[ih * 32 + iw], acc);
    }
  }
  unsigned short bv = (unsigned short)bf16r(acc);
  if (o < 128) {
    kbf[((size_t)b * NC + o) * NTOK + p] = bv;
  } else {
    int c = o - 128;
    int h = c >> 5, d = c & 31;
    vbf[(((size_t)b * HEADS + h) * NTOK + p) * HDIM + d] = bv;
  }
}

// ---------------------------------------------------------------
// attention v3: packed (value|slot) int selection, K-only LDS (64KB), V gather
// from L2 (bf16). grid: 512 = 16 chunks x 4 h x 8 b; block 512 (8 waves).
template <bool FIRST>
__device__ __forceinline__ void extract1(unsigned (&pk)[16], int lane,
                                         const unsigned short* __restrict__ vb,
                                         float& mrow, float& se, float& oac) {
  unsigned mu = wave_maxu(pk[0]);
  unsigned long long bl = __ballot(pk[0] == mu);
  int w = (int)__builtin_ctzll(bl);
  unsigned s = 15u - (mu & 15u);
  int gidx = ((int)(s >> 2) << 8) + (w << 2) + (int)(s & 3);
  unsigned uq = mu & 0xFFFFFFF0u;
  unsigned uo = uq ^ ((unsigned)((int)(~uq) >> 31) | 0x80000000u);
  float fv = __uint_as_float(uo);
  float e;
  if (FIRST) {
    mrow = fv;
    se = 1.f;
    e = 1.f;
  } else {
    e = __expf(fv - mrow);
    se += e;
  }
  float vv = 0.f;
  if (lane < HDIM) {
    unsigned uv = vb[(size_t)gidx * HDIM + lane];
    vv = __uint_as_float(uv << 16);
  }
  oac = fmaf(e, vv, oac);
  if (lane == w) {
#pragma unroll
    for (int i2 = 0; i2 < 15; i2++) pk[i2] = pk[i2 + 1];
    pk[15] = 0u;
  }
}

__launch_bounds__(512, 4)
__global__ void k_attn(const float* __restrict__ qbuf, const unsigned short* __restrict__ kbf,
                       const unsigned short* __restrict__ vbf, const float* __restrict__ rel,
                       const float* __restrict__ temp, float* __restrict__ att) {
  __shared__ __align__(16) unsigned ksh[16384]; // bf16 K [d][n], 64KB

  int bid = blockIdx.x;
  int chunk = bid & 15;
  int h = (bid >> 4) & 3;
  int b = bid >> 6;
  int tid = threadIdx.x;
  int lane = tid & 63;
  int wave = tid >> 6;

  // stage K (already bf16 in global): 8192 uint2 total, 512 threads x 16
  const uint2* kg = (const uint2*)(kbf + ((size_t)b * NC + h * HDIM) * NTOK);
  uint2* kl = (uint2*)ksh;
#pragma unroll
  for (int i = 0; i < 16; i++) kl[tid + i * 512] = kg[tid + i * 512];
  __syncthreads();

  const float tmpr = temp[h];
  const float invt = 1.0f / tmpr;
  const uint2* k2 = (const uint2*)ksh;
  const unsigned short* vb = vbf + ((size_t)(b * HEADS + h)) * NTOK * HDIM;

#pragma unroll 1
  for (int pass = 0; pass < 2; pass++) {
    int qbase = chunk * 64 + wave * 8 + pass * 4;

    // acc init = rel * (1/t)
    v2f acc2[4][8];
    {
      const float4* relp = (const float4*)(rel + (((size_t)b * HEADS + h) * NTOK + qbase) * NTOK);
#pragma unroll
      for (int r = 0; r < 4; r++) {
#pragma unroll
        for (int i = 0; i < 4; i++) {
          float4 rv = relp[r * 256 + i * 64 + lane];
          v2f a0; a0.x = rv.x * invt; a0.y = rv.y * invt;
          v2f a1; a1.x = rv.z * invt; a1.y = rv.w * invt;
          acc2[r][i * 2 + 0] = a0;
          acc2[r][i * 2 + 1] = a1;
        }
      }
    }

    // logits: acc += q_d * K[d][j]
    const float* q0 = qbuf + ((size_t)b * NC + h * HDIM) * NTOK + qbase;
#pragma unroll 4
    for (int d = 0; d < 32; d++) {
      float4 qv = *(const float4*)&q0[d * NTOK];
#pragma unroll
      for (int i = 0; i < 4; i++) {
        uint2 kw = k2[d * 256 + i * 64 + lane];
        v2f klo = bfpair(kw.x);
        v2f khi = bfpair(kw.y);
        v2f q0s = {qv.x, qv.x}, q1s = {qv.y, qv.y}, q2s = {qv.z, qv.z}, q3s = {qv.w, qv.w};
        acc2[0][i * 2 + 0] = __builtin_elementwise_fma(q0s, klo, acc2[0][i * 2 + 0]);
        acc2[0][i * 2 + 1] = __builtin_elementwise_fma(q0s, khi, acc2[0][i * 2 + 1]);
        acc2[1][i * 2 + 0] = __builtin_elementwise_fma(q1s, klo, acc2[1][i * 2 + 0]);
        acc2[1][i * 2 + 1] = __builtin_elementwise_fma(q1s, khi, acc2[1][i * 2 + 1]);
        acc2[2][i * 2 + 0] = __builtin_elementwise_fma(q2s, klo, acc2[2][i * 2 + 0]);
        acc2[2][i * 2 + 1] = __builtin_elementwise_fma(q2s, khi, acc2[2][i * 2 + 1]);
        acc2[3][i * 2 + 0] = __builtin_elementwise_fma(q3s, klo, acc2[3][i * 2 + 0]);
        acc2[3][i * 2 + 1] = __builtin_elementwise_fma(q3s, khi, acc2[3][i * 2 + 1]);
      }
    }

    // pack (value|slot) and per-lane bitonic sort (descending, unsigned min/max)
    unsigned pk[4][16];
#pragma unroll
    for (int r = 0; r < 4; r++) {
#pragma unroll
      for (int j = 0; j < 8; j++) {
        float f0 = tmpr * acc2[r][j].x;
        float f1 = tmpr * acc2[r][j].y;
        pk[r][j * 2 + 0] = (fmap(f0) & 0xFFFFFFF0u) | (15u - (unsigned)(j * 2 + 0));
        pk[r][j * 2 + 1] = (fmap(f1) & 0xFFFFFFF0u) | (15u - (unsigned)(j * 2 + 1));
      }
#pragma unroll
      for (int k = 2; k <= 16; k <<= 1) {
#pragma unroll
        for (int j = k >> 1; j > 0; j >>= 1) {
#pragma unroll
          for (int i = 0; i < 16; i++) {
            int ixj = i ^ j;
            if (ixj > i) {
              unsigned a = pk[r][i], c = pk[r][ixj];
              unsigned mx = a > c ? a : c;
              unsigned mn = a > c ? c : a;
              if ((i & k) == 0) { pk[r][i] = mx; pk[r][ixj] = mn; }
              else              { pk[r][i] = mn; pk[r][ixj] = mx; }
            }
          }
        }
      }
    }

    // interleaved 4-row top-32 select + online softmax + V gather (L2 bf16)
    float mrow[4], se[4], oac[4];
#pragma unroll
    for (int r = 0; r < 4; r++) {
      oac[r] = 0.f;
      extract1<true>(pk[r], lane, vb, mrow[r], se[r], oac[r]);
    }
#pragma unroll 1
    for (int t2 = 1; t2 < TOPK; t2++) {
#pragma unroll
      for (int r = 0; r < 4; r++) {
        extract1<false>(pk[r], lane, vb, mrow[r], se[r], oac[r]);
      }
    }

#pragma unroll
    for (int r = 0; r < 4; r++) {
      if (lane < HDIM) {
        att[((size_t)b * NC + h * HDIM + lane) * NTOK + (qbase + r)] = oac[r] / se[r];
      }
    }
  }
}

// ---------------------------------------------------------------
// bilinear 2x upsample weights (jax scale_and_translate semantics)
__device__ __forceinline__ void bil(int i, int& j0, int& j1, float& wa, float& wb) {
  if (i & 1) {
    j0 = i >> 1; j1 = j0 + 1; wa = 0.75f; wb = 0.25f;
    if (j1 > 31) { j1 = 31; wa = 1.f; wb = 0.f; }
  } else {
    j0 = (i >> 1) - 1; j1 = j0 + 1; wa = 0.25f; wb = 0.75f;
    if (j0 < 0) { j0 = 0; wa = 0.f; wb = 1.f; }
  }
}

// mid = lepe(x) + upsample(att) ; (B,128,64,64)
__global__ void k_mid(const float* __restrict__ x, const float* __restrict__ lepe_w,
                      const float* __restrict__ lepe_b, const float* __restrict__ att,
                      float* __restrict__ mid) {
  int t = blockIdx.x * 256 + threadIdx.x;
  if (t >= NB * NC * NH * NW) return;
  int w = t & 63;
  int h0 = (t >> 6) & 63;
  int bc = t >> 12;
  int c = bc & 127;
  const float* xp = x + (size_t)bc * (NH * NW);
  const float* wp = lepe_w + c * 25;
  float acc = lepe_b[c];
#pragma unroll
  for (int ky = 0; ky < 5; ky++) {
    int ih = h0 + ky - 2;
    if (ih < 0 || ih > 63) continue;
#pragma unroll
    for (int kx = 0; kx < 5; kx++) {
      int iw = w + kx - 2;
      if (iw < 0 || iw > 63) continue;
      acc = fmaf(wp[ky * 5 + kx], xp[ih * 64 + iw], acc);
    }
  }
  int jh0, jh1, jw0, jw1;
  float wha, whb, wwa, wwb;
  bil(h0, jh0, jh1, wha, whb);
  bil(w, jw0, jw1, wwa, wwb);
  const float* ap = att + (size_t)bc * NTOK;
  float up = wha * (wwa * ap[jh0 * 32 + jw0] + wwb * ap[jh0 * 32 + jw1]) +
             whb * (wwa * ap[jh1 * 32 + jw0] + wwb * ap[jh1 * 32 + jw1]);
  mid[t] = acc + up;
}

// ---------------------------------------------------------------
// final 1x1 conv, 32 outputs per thread (mid re-read 4x instead of 16x)
__global__ void k_final(const float* __restrict__ mid, const float* __restrict__ wt,
                        const float* __restrict__ bias, float* __restrict__ out) {
  int p = (blockIdx.x & 15) * 256 + threadIdx.x;
  int rest = blockIdx.x >> 4;
  int cg = rest & 3;
  int b = rest >> 2;
  if (b >= NB) return;
  const float* mp = mid + (size_t)b * NC * (NH * NW) + p;
  const float* wp = wt + cg * 32 * NC;
  float acc[32];
#pragma unroll
  for (int i = 0; i < 32; i++) acc[i] = bias[cg * 32 + i];
  for (int ci = 0; ci < NC; ci++) {
    float mv = mp[ci * 4096];
#pragma unroll
    for (int i = 0; i < 32; i++) acc[i] = fmaf(wp[i * NC + ci], mv, acc[i]);
  }
#pragma unroll
  for (int i = 0; i < 32; i++) out[((size_t)b * NC + cg * 32 + i) * 4096 + p] = acc[i];
}

// ---------------------------------------------------------------
extern "C" void kernel_launch(void* const* d_in, const int* in_sizes, int n_in,
                              void* d_out, int out_size, void* d_ws, size_t ws_size,
                              hipStream_t stream) {
  const float* x      = (const float*)d_in[0];
  const float* y      = (const float*)d_in[1];
  const float* rel    = (const float*)d_in[2];
  const float* q1_w   = (const float*)d_in[3];
  const float* q1_b   = (const float*)d_in[4];
  const float* q2_w   = (const float*)d_in[5];
  const float* q2_b   = (const float*)d_in[6];
  const float* kv1_w  = (const float*)d_in[7];
  const float* kv1_b  = (const float*)d_in[8];
  const float* kv2_w  = (const float*)d_in[9];
  const float* kv2_b  = (const float*)d_in[10];
  const float* lepe_w = (const float*)d_in[11];
  const float* lepe_b = (const float*)d_in[12];
  const float* out_w  = (const float*)d_in[13];
  const float* out_b  = (const float*)d_in[14];
  const float* temp   = (const float*)d_in[15];
  float* out = (float*)d_out;

  float* ws = (float*)d_ws;
  const size_t SP = (size_t)NB * NC * NTOK;   // 1,048,576
  float* xp     = ws;                  // SP
  float* yp     = xp + SP;             // SP
  float* q1buf  = yp + SP;             // SP
  float* kv1buf = q1buf + SP;          // 2*SP
  float* qbuf   = kv1buf + 2 * SP;     // SP
  float* attb   = qbuf + SP;           // SP
  float* mid    = attb + SP;           // 4*SP
  unsigned short* kbf = (unsigned short*)(mid + 4 * SP);  // SP ushorts (2MB)
  unsigned short* vbf = kbf + SP;                         // SP ushorts (2MB)

  k_pool<<<8192, 256, 0, stream>>>(x, y, xp, yp);
  k_conv1x1<128><<<256, 256, 0, stream>>>(xp, q1_w, q1_b, q1buf);
  k_dw3<<<4096, 256, 0, stream>>>(q1buf, q2_w, q2_b, qbuf);
  k_conv1x1<256><<<512, 256, 0, stream>>>(yp, kv1_w, kv1_b, kv1buf);
  k_kv2<<<8192, 256, 0, stream>>>(kv1buf, kv2_w, kv2_b, kbf, vbf);
  k_attn<<<512, 512, 0, stream>>>(qbuf, kbf, vbf, rel, temp, attb);
  k_mid<<<16384, 256, 0, stream>>>(x, lepe_w, lepe_b, attb, mid);
  k_final<<<512, 256, 0, stream>>>(mid, out_w, out_b, out);
}

// Round 6
// 315.736 us; speedup vs baseline: 2.9956x; 1.1277x over previous
//
#include <hip/hip_runtime.h>

// Problem constants
#define NB 8
#define NC 128
#define NH 64
#define NW 64
#define HEADS 4
#define HP 32
#define WP 32
#define NTOK 1024     // HP*WP
#define TOPK 32
#define HDIM 32

typedef float v2f __attribute__((ext_vector_type(2)));

// ---------------------------------------------------------------
// bf16 helpers (round-to-nearest-even)
__device__ __forceinline__ unsigned bf16r(float f) {
  unsigned u = __float_as_uint(f);
  return (u + 0x7FFFu + ((u >> 16) & 1u)) >> 16;
}

// monotone float->uint map (order-preserving)
__device__ __forceinline__ unsigned fmap(float f) {
  unsigned u = __float_as_uint(f);
  return u ^ ((unsigned)((int)u >> 31) | 0x80000000u);
}

__device__ __forceinline__ v2f bfpair(unsigned w) {
  v2f r;
  r.x = __uint_as_float(w << 16);
  r.y = __uint_as_float(w & 0xFFFF0000u);
  return r;
}

// DPP wave64 max-reduce on unsigned; result broadcast via readlane(63)
__device__ __forceinline__ unsigned wave_maxu(unsigned v) {
#define ST(ctrl)                                                                     \
  {                                                                                  \
    unsigned o = (unsigned)__builtin_amdgcn_update_dpp(0, (int)v, ctrl, 0xF, 0xF, true); \
    v = v > o ? v : o;                                                               \
  }
  ST(0xB1)   // quad_perm [1,0,3,2]
  ST(0x4E)   // quad_perm [2,3,0,1]
  ST(0x141)  // row_half_mirror
  ST(0x140)  // row_mirror
  ST(0x142)  // row_bcast:15
  ST(0x143)  // row_bcast:31
#undef ST
  return (unsigned)__builtin_amdgcn_readlane((int)v, 63);
}

// DPP wave64 float sum-reduce; result broadcast via readlane(63)
__device__ __forceinline__ float wave_sumf(float v) {
#define STA(ctrl)                                                                    \
  v += __int_as_float(__builtin_amdgcn_update_dpp(0, __float_as_int(v), ctrl, 0xF, 0xF, true));
  STA(0xB1)
  STA(0x4E)
  STA(0x141)
  STA(0x140)
  STA(0x142)
  STA(0x143)
#undef STA
  return __int_as_float(__builtin_amdgcn_readlane(__float_as_int(v), 63));
}

// ---------------------------------------------------------------
// avg pool 2x2 on x and y
__global__ void k_pool(const float* __restrict__ x, const float* __restrict__ y,
                       float* __restrict__ xp, float* __restrict__ yp) {
  int idx = blockIdx.x * 256 + threadIdx.x;
  const int total = NB * NC * HP * WP; // 1,048,576
  if (idx >= 2 * total) return;
  bool isY = idx >= total;
  int i = isY ? idx - total : idx;
  int pw = i & 31, ph = (i >> 5) & 31, bc = i >> 10;
  const float* src = (isY ? y : x) + ((size_t)bc * 64 + ph * 2) * 64 + pw * 2;
  float v = 0.25f * (src[0] + src[1] + src[64] + src[65]);
  (isY ? yp : xp)[i] = v;
}

// ---------------------------------------------------------------
// 1x1 conv, 16 outputs per thread (weights wave-uniform -> s_loads)
template <int CO>
__global__ void k_conv1x1(const float* __restrict__ in, const float* __restrict__ wt,
                          const float* __restrict__ bias, float* __restrict__ out) {
  const int CG = CO / 16;
  int p = (blockIdx.x & 3) * 256 + threadIdx.x;
  int rest = blockIdx.x >> 2;
  int cg = rest % CG;
  int b = rest / CG;
  if (b >= NB) return;
  const float* ip = in + (size_t)b * NC * NTOK + p;
  const float* wp = wt + cg * 16 * NC;
  float acc[16];
#pragma unroll
  for (int i = 0; i < 16; i++) acc[i] = bias[cg * 16 + i];
  for (int ci = 0; ci < NC; ci++) {
    float mv = ip[ci * NTOK];
#pragma unroll
    for (int i = 0; i < 16; i++) acc[i] = fmaf(wp[i * NC + ci], mv, acc[i]);
  }
#pragma unroll
  for (int i = 0; i < 16; i++) out[((size_t)b * CO + cg * 16 + i) * NTOK + p] = acc[i];
}

// ---------------------------------------------------------------
// depthwise 3x3 pad=1 on (B,128,32,32)
__global__ void k_dw3(const float* __restrict__ in, const float* __restrict__ wt,
                      const float* __restrict__ bias, float* __restrict__ out) {
  int t = blockIdx.x * 256 + threadIdx.x;
  if (t >= NB * NC * NTOK) return;
  int p = t & 1023;
  int pw = p & 31, ph = p >> 5;
  int bc = t >> 10;
  int c = bc & 127;
  const float* ip = in + (size_t)bc * NTOK;
  const float* wp = wt + c * 9;
  float acc = bias[c];
#pragma unroll
  for (int ky = 0; ky < 3; ky++) {
    int ih = ph + ky - 1;
    if (ih < 0 || ih > 31) continue;
#pragma unroll
    for (int kx = 0; kx < 3; kx++) {
      int iw = pw + kx - 1;
      if (iw < 0 || iw > 31) continue;
      acc = fmaf(wp[ky * 3 + kx], ip[ih * 32 + iw], acc);
    }
  }
  out[t] = acc;
}

// ---------------------------------------------------------------
// grouped 3x3 (groups=128) on kv1 (B,256,32,32); emits bf16 K and bf16 V
__global__ void k_kv2(const float* __restrict__ in, const float* __restrict__ wt,
                      const float* __restrict__ bias, unsigned short* __restrict__ kbf,
                      unsigned short* __restrict__ vbf) {
  int t = blockIdx.x * 256 + threadIdx.x;
  if (t >= NB * 256 * NTOK) return;
  int p = t & 1023;
  int pw = p & 31, ph = p >> 5;
  int bo = t >> 10;
  int o = bo & 255;
  int b = bo >> 8;
  int g = o >> 1;
  const float* ip0 = in + ((size_t)b * 256 + 2 * g) * NTOK;
  const float* ip1 = ip0 + NTOK;
  const float* wp = wt + o * 18; // [2][3][3]
  float acc = bias[o];
#pragma unroll
  for (int ky = 0; ky < 3; ky++) {
    int ih = ph + ky - 1;
    if (ih < 0 || ih > 31) continue;
#pragma unroll
    for (int kx = 0; kx < 3; kx++) {
      int iw = pw + kx - 1;
      if (iw < 0 || iw > 31) continue;
      float w0 = wp[ky * 3 + kx];
      float w1 = wp[9 + ky * 3 + kx];
      acc = fmaf(w0, ip0[ih * 32 + iw], acc);
      acc = fmaf(w1, ip1[ih * 32 + iw], acc);
    }
  }
  unsigned short bv = (unsigned short)bf16r(acc);
  if (o < 128) {
    kbf[((size_t)b * NC + o) * NTOK + p] = bv;
  } else {
    int c = o - 128;
    int h = c >> 5, d = c & 31;
    vbf[(((size_t)b * HEADS + h) * NTOK + p) * HDIM + d] = bv;
  }
}

// ---------------------------------------------------------------
// attention v4: phase-split top-32 selection.
// Phase 1: serial DPP-max extraction recording (key, winner-lane) via cndmask.
// Phase 2: parallel exp/sum + pipelined V gather with readlane-broadcast weights.
__launch_bounds__(512, 4)
__global__ void k_attn(const float* __restrict__ qbuf, const unsigned short* __restrict__ kbf,
                       const unsigned short* __restrict__ vbf, const float* __restrict__ rel,
                       const float* __restrict__ temp, float* __restrict__ att) {
  __shared__ __align__(16) unsigned ksh[16384]; // bf16 K [d][n], 64KB

  int bid = blockIdx.x;
  int chunk = bid & 15;
  int h = (bid >> 4) & 3;
  int b = bid >> 6;
  int tid = threadIdx.x;
  int lane = tid & 63;
  int wave = tid >> 6;

  // stage K (already bf16 in global): 8192 uint2 total, 512 threads x 16
  const uint2* kg = (const uint2*)(kbf + ((size_t)b * NC + h * HDIM) * NTOK);
  uint2* kl = (uint2*)ksh;
#pragma unroll
  for (int i = 0; i < 16; i++) kl[tid + i * 512] = kg[tid + i * 512];
  __syncthreads();

  const float tmpr = temp[h];
  const float invt = 1.0f / tmpr;
  const uint2* k2 = (const uint2*)ksh;
  const unsigned short* vb = vbf + ((size_t)(b * HEADS + h)) * NTOK * HDIM;
  int vlane = lane & 31;  // lanes 32-63 mirror 0-31 (harmless, never written out)

#pragma unroll 1
  for (int pass = 0; pass < 2; pass++) {
    int qbase = chunk * 64 + wave * 8 + pass * 4;

    // acc init = rel * (1/t)
    v2f acc2[4][8];
    {
      const float4* relp = (const float4*)(rel + (((size_t)b * HEADS + h) * NTOK + qbase) * NTOK);
#pragma unroll
      for (int r = 0; r < 4; r++) {
#pragma unroll
        for (int i = 0; i < 4; i++) {
          float4 rv = relp[r * 256 + i * 64 + lane];
          v2f a0; a0.x = rv.x * invt; a0.y = rv.y * invt;
          v2f a1; a1.x = rv.z * invt; a1.y = rv.w * invt;
          acc2[r][i * 2 + 0] = a0;
          acc2[r][i * 2 + 1] = a1;
        }
      }
    }

    // logits: acc += q_d * K[d][j]
    const float* q0 = qbuf + ((size_t)b * NC + h * HDIM) * NTOK + qbase;
#pragma unroll 4
    for (int d = 0; d < 32; d++) {
      float4 qv = *(const float4*)&q0[d * NTOK];
#pragma unroll
      for (int i = 0; i < 4; i++) {
        uint2 kw = k2[d * 256 + i * 64 + lane];
        v2f klo = bfpair(kw.x);
        v2f khi = bfpair(kw.y);
        v2f q0s = {qv.x, qv.x}, q1s = {qv.y, qv.y}, q2s = {qv.z, qv.z}, q3s = {qv.w, qv.w};
        acc2[0][i * 2 + 0] = __builtin_elementwise_fma(q0s, klo, acc2[0][i * 2 + 0]);
        acc2[0][i * 2 + 1] = __builtin_elementwise_fma(q0s, khi, acc2[0][i * 2 + 1]);
        acc2[1][i * 2 + 0] = __builtin_elementwise_fma(q1s, klo, acc2[1][i * 2 + 0]);
        acc2[1][i * 2 + 1] = __builtin_elementwise_fma(q1s, khi, acc2[1][i * 2 + 1]);
        acc2[2][i * 2 + 0] = __builtin_elementwise_fma(q2s, klo, acc2[2][i * 2 + 0]);
        acc2[2][i * 2 + 1] = __builtin_elementwise_fma(q2s, khi, acc2[2][i * 2 + 1]);
        acc2[3][i * 2 + 0] = __builtin_elementwise_fma(q3s, klo, acc2[3][i * 2 + 0]);
        acc2[3][i * 2 + 1] = __builtin_elementwise_fma(q3s, khi, acc2[3][i * 2 + 1]);
      }
    }

    // pack (value|slot) and per-lane bitonic sort (descending, unsigned min/max)
    unsigned pk[4][16];
#pragma unroll
    for (int r = 0; r < 4; r++) {
#pragma unroll
      for (int j = 0; j < 8; j++) {
        float f0 = tmpr * acc2[r][j].x;
        float f1 = tmpr * acc2[r][j].y;
        pk[r][j * 2 + 0] = (fmap(f0) & 0xFFFFFFF0u) | (15u - (unsigned)(j * 2 + 0));
        pk[r][j * 2 + 1] = (fmap(f1) & 0xFFFFFFF0u) | (15u - (unsigned)(j * 2 + 1));
      }
#pragma unroll
      for (int k = 2; k <= 16; k <<= 1) {
#pragma unroll
        for (int j = k >> 1; j > 0; j >>= 1) {
#pragma unroll
          for (int i = 0; i < 16; i++) {
            int ixj = i ^ j;
            if (ixj > i) {
              unsigned a = pk[r][i], c = pk[r][ixj];
              unsigned mx = a > c ? a : c;
              unsigned mn = a > c ? c : a;
              if ((i & k) == 0) { pk[r][i] = mx; pk[r][ixj] = mn; }
              else              { pk[r][i] = mn; pk[r][ixj] = mx; }
            }
          }
        }
      }
    }

    // ---- phase 1: top-32 selection (no gather, no exp in chain) ----
    // lane t2 of sval[r]/swl[r] records iteration t2's (key, winner lane)
    unsigned sval[4] = {0u, 0u, 0u, 0u};
    unsigned swl[4] = {0u, 0u, 0u, 0u};
#pragma unroll 1
    for (int t2 = 0; t2 < TOPK; t2++) {
      bool rec = (lane == t2);
#pragma unroll
      for (int r = 0; r < 4; r++) {
        unsigned mu = wave_maxu(pk[r][0]);
        unsigned long long bl = __ballot(pk[r][0] == mu);
        int w = (int)__builtin_ctzll(bl);
        sval[r] = rec ? mu : sval[r];
        swl[r] = rec ? (unsigned)w : swl[r];
        bool win = (lane == w);
#pragma unroll
        for (int s = 0; s < 12; s++) pk[r][s] = win ? pk[r][s + 1] : pk[r][s];
      }
    }

    // ---- phase 2: parallel softmax + pipelined V gather ----
#pragma unroll
    for (int r = 0; r < 4; r++) {
      // decode recorded key -> logit value (lanes 0..31 valid)
      unsigned uq = sval[r] & 0xFFFFFFF0u;
      unsigned uo = uq ^ ((unsigned)((int)(~uq) >> 31) | 0x80000000u);
      float fv = __uint_as_float(uo);
      float m = __int_as_float(__builtin_amdgcn_readfirstlane(__float_as_int(fv)));
      float e = __expf(fv - m);
      e = (lane < TOPK) ? e : 0.f;
      float se = wave_sumf(e);

      float oacc = 0.f;
#pragma unroll
      for (int t = 0; t < TOPK; t++) {
        unsigned mus = (unsigned)__builtin_amdgcn_readlane((int)sval[r], t);
        int ws = __builtin_amdgcn_readlane((int)swl[r], t);
        unsigned s = 15u - (mus & 15u);
        int gidx = ((int)(s >> 2) << 8) + (ws << 2) + (int)(s & 3);
        float es = __int_as_float(__builtin_amdgcn_readlane(__float_as_int(e), t));
        float vv = __uint_as_float((unsigned)vb[(size_t)gidx * HDIM + vlane] << 16);
        oacc = fmaf(es, vv, oacc);
      }

      if (lane < HDIM) {
        att[((size_t)b * NC + h * HDIM + lane) * NTOK + (qbase + r)] = oacc / se;
      }
    }
  }
}

// ---------------------------------------------------------------
// bilinear 2x upsample weights (jax scale_and_translate semantics)
__device__ __forceinline__ void bil(int i, int& j0, int& j1, float& wa, float& wb) {
  if (i & 1) {
    j0 = i >> 1; j1 = j0 + 1; wa = 0.75f; wb = 0.25f;
    if (j1 > 31) { j1 = 31; wa = 1.f; wb = 0.f; }
  } else {
    j0 = (i >> 1) - 1; j1 = j0 + 1; wa = 0.25f; wb = 0.75f;
    if (j0 < 0) { j0 = 0; wa = 0.f; wb = 1.f; }
  }
}

// mid = lepe(x) + upsample(att) ; (B,128,64,64)
__global__ void k_mid(const float* __restrict__ x, const float* __restrict__ lepe_w,
                      const float* __restrict__ lepe_b, const float* __restrict__ att,
                      float* __restrict__ mid) {
  int t = blockIdx.x * 256 + threadIdx.x;
  if (t >= NB * NC * NH * NW) return;
  int w = t & 63;
  int h0 = (t >> 6) & 63;
  int bc = t >> 12;
  int c = bc & 127;
  const float* xp = x + (size_t)bc * (NH * NW);
  const float* wp = lepe_w + c * 25;
  float acc = lepe_b[c];
#pragma unroll
  for (int ky = 0; ky < 5; ky++) {
    int ih = h0 + ky - 2;
    if (ih < 0 || ih > 63) continue;
#pragma unroll
    for (int kx = 0; kx < 5; kx++) {
      int iw = w + kx - 2;
      if (iw < 0 || iw > 63) continue;
      acc = fmaf(wp[ky * 5 + kx], xp[ih * 64 + iw], acc);
    }
  }
  int jh0, jh1, jw0, jw1;
  float wha, whb, wwa, wwb;
  bil(h0, jh0, jh1, wha, whb);
  bil(w, jw0, jw1, wwa, wwb);
  const float* ap = att + (size_t)bc * NTOK;
  float up = wha * (wwa * ap[jh0 * 32 + jw0] + wwb * ap[jh0 * 32 + jw1]) +
             whb * (wwa * ap[jh1 * 32 + jw0] + wwb * ap[jh1 * 32 + jw1]);
  mid[t] = acc + up;
}

// ---------------------------------------------------------------
// final 1x1 conv, 32 outputs per thread (mid re-read 4x instead of 16x)
__global__ void k_final(const float* __restrict__ mid, const float* __restrict__ wt,
                        const float* __restrict__ bias, float* __restrict__ out) {
  int p = (blockIdx.x & 15) * 256 + threadIdx.x;
  int rest = blockIdx.x >> 4;
  int cg = rest & 3;
  int b = rest >> 2;
  if (b >= NB) return;
  const float* mp = mid + (size_t)b * NC * (NH * NW) + p;
  const float* wp = wt + cg * 32 * NC;
  float acc[32];
#pragma unroll
  for (int i = 0; i < 32; i++) acc[i] = bias[cg * 32 + i];
  for (int ci = 0; ci < NC; ci++) {
    float mv = mp[ci * 4096];
#pragma unroll
    for (int i = 0; i < 32; i++) acc[i] = fmaf(wp[i * NC + ci], mv, acc[i]);
  }
#pragma unroll
  for (int i = 0; i < 32; i++) out[((size_t)b * NC + cg * 32 + i) * 4096 + p] = acc[i];
}

// ---------------------------------------------------------------
extern "C" void kernel_launch(void* const* d_in, const int* in_sizes, int n_in,
                              void* d_out, int out_size, void* d_ws, size_t ws_size,
                              hipStream_t stream) {
  const float* x      = (const float*)d_in[0];
  const float* y      = (const float*)d_in[1];
  const float* rel    = (const float*)d_in[2];
  const float* q1_w   = (const float*)d_in[3];
  const float* q1_b   = (const float*)d_in[4];
  const float* q2_w   = (const float*)d_in[5];
  const float* q2_b   = (const float*)d_in[6];
  const float* kv1_w  = (const float*)d_in[7];
  const float* kv1_b  = (const float*)d_in[8];
  const float* kv2_w  = (const float*)d_in[9];
  const float* kv2_b  = (const float*)d_in[10];
  const float* lepe_w = (const float*)d_in[11];
  const float* lepe_b = (const float*)d_in[12];
  const float* out_w  = (const float*)d_in[13];
  const float* out_b  = (const float*)d_in[14];
  const float* temp   = (const float*)d_in[15];
  float* out = (float*)d_out;

  float* ws = (float*)d_ws;
  const size_t SP = (size_t)NB * NC * NTOK;   // 1,048,576
  float* xp     = ws;                  // SP
  float* yp     = xp + SP;             // SP
  float* q1buf  = yp + SP;             // SP
  float* kv1buf = q1buf + SP;          // 2*SP
  float* qbuf   = kv1buf + 2 * SP;     // SP
  float* attb   = qbuf + SP;           // SP
  float* mid    = attb + SP;           // 4*SP
  unsigned short* kbf = (unsigned short*)(mid + 4 * SP);  // SP ushorts (2MB)
  unsigned short* vbf = kbf + SP;                         // SP ushorts (2MB)

  k_pool<<<8192, 256, 0, stream>>>(x, y, xp, yp);
  k_conv1x1<128><<<256, 256, 0, stream>>>(xp, q1_w, q1_b, q1buf);
  k_dw3<<<4096, 256, 0, stream>>>(q1buf, q2_w, q2_b, qbuf);
  k_conv1x1<256><<<512, 256, 0, stream>>>(yp, kv1_w, kv1_b, kv1buf);
  k_kv2<<<8192, 256, 0, stream>>>(kv1buf, kv2_w, kv2_b, kbf, vbf);
  k_attn<<<512, 512, 0, stream>>>(qbuf, kbf, vbf, rel, temp, attb);
  k_mid<<<16384, 256, 0, stream>>>(x, lepe_w, lepe_b, attb, mid);
  k_final<<<512, 256, 0, stream>>>(mid, out_w, out_b, out);
}